// Round 1
// baseline (5514.709 us; speedup 1.0000x reference)
//
#include <hip/hip_runtime.h>
#include <math.h>

constexpr int NN = 100000;   // nodes
constexpr int NE = 3200000;  // edges
constexpr int DF = 512;      // in features
constexpr int NH = 16;       // hidden
constexpr int NC = 40;       // classes

// ---------------------------------------------------------------- degree
__global__ void k_deg_init(float* __restrict__ deg) {
    int i = blockIdx.x * blockDim.x + threadIdx.x;
    if (i < NN) deg[i] = 1.0f;  // self-loop
}

__global__ void k_deg_count(const int* __restrict__ dst, float* __restrict__ deg) {
    int i = blockIdx.x * blockDim.x + threadIdx.x;
    if (i < NE) atomicAdd(&deg[dst[i]], 1.0f);
}

__global__ void k_dinv(float* __restrict__ deg) {
    int i = blockIdx.x * blockDim.x + threadIdx.x;
    if (i < NN) deg[i] = rsqrtf(deg[i]);  // deg >= 1 always
}

// ---------------------------------------------------------------- layer-1 GEMM
// h1 = x @ W1  (100000x512 @ 512x16), fused: agg1 = h1 * dinv^2 (self-loop term)
__global__ __launch_bounds__(256) void k_gemm1(
    const float* __restrict__ x, const float* __restrict__ W1,
    const float* __restrict__ dinv, float* __restrict__ h1,
    float* __restrict__ agg1) {
    __shared__ __align__(16) float sW[DF * NH];   // 32 KB, whole W1
    __shared__ __align__(16) float sX[64][68];    // 64 rows x 64 k, pad->68 (2-way max)
    const int t = threadIdx.x;

    // stage W1 (8192 floats, 32/thread)
    for (int i = t * 4; i < DF * NH; i += 256 * 4)
        *(float4*)&sW[i] = *(const float4*)&W1[i];

    const int row0 = blockIdx.x * 64;
    const int r   = t >> 2;   // local row 0..63
    const int og  = t & 3;    // output quad: cols og*4 .. og*4+3
    float acc0 = 0.f, acc1 = 0.f, acc2 = 0.f, acc3 = 0.f;

    for (int kc = 0; kc < DF; kc += 64) {
        __syncthreads();
        // stage x[row0:+64][kc:+64]; 16 lanes per row, float4 each
        const int lc4 = t & 15;
        #pragma unroll
        for (int p = 0; p < 4; ++p) {
            const int lr = (t >> 4) + p * 16;
            const int gr = row0 + lr;
            float4 v = make_float4(0.f, 0.f, 0.f, 0.f);
            if (gr < NN) v = *(const float4*)&x[(size_t)gr * DF + kc + lc4 * 4];
            *(float4*)&sX[lr][lc4 * 4] = v;
        }
        __syncthreads();
        #pragma unroll 16
        for (int k = 0; k < 64; ++k) {
            const float xv = sX[r][k];
            const float4 w = *(const float4*)&sW[(kc + k) * NH + og * 4];
            acc0 = fmaf(xv, w.x, acc0);
            acc1 = fmaf(xv, w.y, acc1);
            acc2 = fmaf(xv, w.z, acc2);
            acc3 = fmaf(xv, w.w, acc3);
        }
    }
    const int gr = row0 + r;
    if (gr < NN) {
        const float di = dinv[gr];
        const float s  = di * di;
        *(float4*)&h1[gr * NH + og * 4]   = make_float4(acc0, acc1, acc2, acc3);
        *(float4*)&agg1[gr * NH + og * 4] = make_float4(acc0 * s, acc1 * s, acc2 * s, acc3 * s);
    }
}

// ---------------------------------------------------------------- edge aggregation
// agg[dst] += h[src] * dinv[src]*dinv[dst], 16 floats per edge
__global__ void k_agg_edges(const int* __restrict__ src, const int* __restrict__ dst,
                            const float* __restrict__ dinv,
                            const float* __restrict__ h, float* __restrict__ agg) {
    int i = blockIdx.x * blockDim.x + threadIdx.x;
    if (i >= NE) return;
    const int s = src[i], d = dst[i];
    const float nm = dinv[s] * dinv[d];
    const float4* hs = (const float4*)&h[(size_t)s * NH];
    float* ad = &agg[(size_t)d * NH];
    #pragma unroll
    for (int q = 0; q < 4; ++q) {
        const float4 v = hs[q];
        atomicAdd(&ad[q * 4 + 0], v.x * nm);
        atomicAdd(&ad[q * 4 + 1], v.y * nm);
        atomicAdd(&ad[q * 4 + 2], v.z * nm);
        atomicAdd(&ad[q * 4 + 3], v.w * nm);
    }
}

// ---------------------------------------------------------------- relu(bias) + layer-2 self-loop init
// agg1 <- relu(agg1 + b1);  agg2 <- relu_val * dinv^2
__global__ void k_relu_init(float* __restrict__ agg1, const float* __restrict__ b1,
                            const float* __restrict__ dinv, float* __restrict__ agg2) {
    int i = blockIdx.x * blockDim.x + threadIdx.x;
    if (i >= NN * NH) return;
    const int row = i >> 4, col = i & 15;
    float v = agg1[i] + b1[col];
    v = fmaxf(v, 0.0f);
    agg1[i] = v;
    const float di = dinv[row];
    agg2[i] = v * di * di;
}

// ---------------------------------------------------------------- final: out = log_softmax(agg2 @ W2 + b2)
__global__ __launch_bounds__(256) void k_final(
    const float* __restrict__ agg2, const float* __restrict__ W2,
    const float* __restrict__ b2, float* __restrict__ out) {
    __shared__ float sW[NH * NC];  // 640 floats
    __shared__ float sb[NC];
    const int t = threadIdx.x;
    for (int i = t; i < NH * NC; i += 256) sW[i] = W2[i];
    if (t < NC) sb[t] = b2[t];
    __syncthreads();

    const int row = blockIdx.x * blockDim.x + t;
    if (row >= NN) return;

    float h[NH];
    const float4* ap = (const float4*)&agg2[(size_t)row * NH];
    #pragma unroll
    for (int q = 0; q < 4; ++q) {
        const float4 a = ap[q];
        h[q * 4 + 0] = a.x; h[q * 4 + 1] = a.y; h[q * 4 + 2] = a.z; h[q * 4 + 3] = a.w;
    }
    float z[NC];
    #pragma unroll
    for (int c = 0; c < NC; ++c) z[c] = sb[c];
    #pragma unroll
    for (int k = 0; k < NH; ++k) {
        const float hv = h[k];
        #pragma unroll
        for (int c = 0; c < NC; ++c) z[c] = fmaf(hv, sW[k * NC + c], z[c]);
    }
    float m = z[0];
    #pragma unroll
    for (int c = 1; c < NC; ++c) m = fmaxf(m, z[c]);
    float sum = 0.f;
    #pragma unroll
    for (int c = 0; c < NC; ++c) sum += __expf(z[c] - m);
    const float lse = m + __logf(sum);
    #pragma unroll
    for (int c = 0; c < NC; ++c) out[(size_t)row * NC + c] = z[c] - lse;
}

// ---------------------------------------------------------------- launch
extern "C" void kernel_launch(void* const* d_in, const int* in_sizes, int n_in,
                              void* d_out, int out_size, void* d_ws, size_t ws_size,
                              hipStream_t stream) {
    const float* x  = (const float*)d_in[0];
    const int*   ei = (const int*)d_in[1];   // [2, NE] flat; per harness: integer -> int32
    const float* W1 = (const float*)d_in[2];
    const float* b1 = (const float*)d_in[3];
    const float* W2 = (const float*)d_in[4];
    const float* b2 = (const float*)d_in[5];
    float* out = (float*)d_out;

    float* ws   = (float*)d_ws;
    float* dinv = ws;                    // NN
    float* h1   = ws + NN;               // NN*NH
    float* agg1 = ws + NN + NN * NH;     // NN*NH
    float* agg2 = ws + NN + 2 * NN * NH; // NN*NH

    const int* esrc = ei;
    const int* edst = ei + NE;

    const dim3 B(256);
    k_deg_init <<<(NN + 255) / 256, B, 0, stream>>>(dinv);
    k_deg_count<<<(NE + 255) / 256, B, 0, stream>>>(edst, dinv);
    k_dinv     <<<(NN + 255) / 256, B, 0, stream>>>(dinv);
    k_gemm1    <<<(NN + 63) / 64,   B, 0, stream>>>(x, W1, dinv, h1, agg1);
    k_agg_edges<<<(NE + 255) / 256, B, 0, stream>>>(esrc, edst, dinv, h1, agg1);
    k_relu_init<<<(NN * NH + 255) / 256, B, 0, stream>>>(agg1, b1, dinv, agg2);
    k_agg_edges<<<(NE + 255) / 256, B, 0, stream>>>(esrc, edst, dinv, agg1, agg2);
    k_final    <<<(NN + 255) / 256, B, 0, stream>>>(agg2, W2, b2, out);
}

// Round 2
// 686.136 us; speedup vs baseline: 8.0373x; 8.0373x over previous
//
#include <hip/hip_runtime.h>
#include <math.h>

constexpr int NN = 100000;   // nodes
constexpr int NE = 3200000;  // edges
constexpr int DF = 512;      // in features
constexpr int NH = 16;       // hidden
constexpr int NC = 40;       // classes

constexpr int CHUNK  = 1024;                         // scan chunk (4 per thread, 256 thr)
constexpr int NCHUNK = (NN + CHUNK - 1) / CHUNK;     // 98 (<= 128)

// ---------------------------------------------------------------- degree histogram
__global__ void k_zero_deg(int* __restrict__ degi) {
    int i = blockIdx.x * blockDim.x + threadIdx.x;
    if (i < NN) degi[i] = 0;
}

__global__ void k_deg_count(const int* __restrict__ dst, int* __restrict__ degi) {
    int i = blockIdx.x * blockDim.x + threadIdx.x;
    if (i < NE) atomicAdd(&degi[dst[i]], 1);
}

__global__ void k_dinv(const int* __restrict__ degi, float* __restrict__ dinv) {
    int i = blockIdx.x * blockDim.x + threadIdx.x;
    if (i < NN) dinv[i] = rsqrtf((float)(degi[i] + 1));  // +1 self-loop
}

// ---------------------------------------------------------------- exclusive scan (3 kernels)
__global__ __launch_bounds__(256) void k_chunk_sum(const int* __restrict__ degi,
                                                   int* __restrict__ part) {
    __shared__ int s[256];
    const int b = blockIdx.x, t = threadIdx.x;
    const int base = b * CHUNK + t * 4;
    int v = 0;
    #pragma unroll
    for (int j = 0; j < 4; ++j) { int idx = base + j; if (idx < NN) v += degi[idx]; }
    s[t] = v; __syncthreads();
    for (int off = 128; off > 0; off >>= 1) {
        if (t < off) s[t] += s[t + off];
        __syncthreads();
    }
    if (t == 0) part[b] = s[0];
}

__global__ void k_scan_part(int* __restrict__ part) {  // 1 block, 128 threads
    __shared__ int s[128];
    const int t = threadIdx.x;
    const int v = (t < NCHUNK) ? part[t] : 0;
    s[t] = v; __syncthreads();
    for (int off = 1; off < 128; off <<= 1) {
        int u = (t >= off) ? s[t - off] : 0;
        __syncthreads();
        s[t] += u;
        __syncthreads();
    }
    if (t < NCHUNK) part[t] = s[t] - v;  // exclusive
}

__global__ __launch_bounds__(256) void k_chunk_scan(const int* __restrict__ degi,
                                                    const int* __restrict__ part,
                                                    int* __restrict__ row_start,
                                                    int* __restrict__ cursor) {
    __shared__ int s[256];
    const int b = blockIdx.x, t = threadIdx.x;
    const int base = b * CHUNK + t * 4;
    int v[4]; int sum = 0;
    #pragma unroll
    for (int j = 0; j < 4; ++j) {
        int idx = base + j;
        v[j] = (idx < NN) ? degi[idx] : 0;
        sum += v[j];
    }
    s[t] = sum; __syncthreads();
    const int mine = sum;
    for (int off = 1; off < 256; off <<= 1) {
        int u = (t >= off) ? s[t - off] : 0;
        __syncthreads();
        s[t] += u;
        __syncthreads();
    }
    int run = part[b] + s[t] - mine;  // exclusive offset of this thread's 4 elems
    #pragma unroll
    for (int j = 0; j < 4; ++j) {
        int idx = base + j;
        if (idx < NN) { row_start[idx] = run; cursor[idx] = run; }
        run += v[j];
    }
}

// ---------------------------------------------------------------- scatter edges by dst
__global__ void k_scatter(const int* __restrict__ src, const int* __restrict__ dst,
                          int* __restrict__ cursor, int* __restrict__ esrc_s) {
    int i = blockIdx.x * blockDim.x + threadIdx.x;
    if (i >= NE) return;
    const int d = dst[i];
    const int pos = atomicAdd(&cursor[d], 1);
    esrc_s[pos] = src[i];
}

// ---------------------------------------------------------------- layer-1 GEMM: h1 = x @ W1
__global__ __launch_bounds__(256) void k_gemm1(
    const float* __restrict__ x, const float* __restrict__ W1,
    float* __restrict__ h1) {
    __shared__ __align__(16) float sW[DF * NH];   // 32 KB, whole W1
    __shared__ __align__(16) float sX[64][68];    // 64 rows x 64 k, pad->68
    const int t = threadIdx.x;

    for (int i = t * 4; i < DF * NH; i += 256 * 4)
        *(float4*)&sW[i] = *(const float4*)&W1[i];

    const int row0 = blockIdx.x * 64;
    const int r  = t >> 2;   // local row 0..63
    const int og = t & 3;    // output quad
    float acc0 = 0.f, acc1 = 0.f, acc2 = 0.f, acc3 = 0.f;

    for (int kc = 0; kc < DF; kc += 64) {
        __syncthreads();
        const int lc4 = t & 15;
        #pragma unroll
        for (int p = 0; p < 4; ++p) {
            const int lr = (t >> 4) + p * 16;
            const int gr = row0 + lr;
            float4 v = make_float4(0.f, 0.f, 0.f, 0.f);
            if (gr < NN) v = *(const float4*)&x[(size_t)gr * DF + kc + lc4 * 4];
            *(float4*)&sX[lr][lc4 * 4] = v;
        }
        __syncthreads();
        #pragma unroll 16
        for (int k = 0; k < 64; ++k) {
            const float xv = sX[r][k];
            const float4 w = *(const float4*)&sW[(kc + k) * NH + og * 4];
            acc0 = fmaf(xv, w.x, acc0);
            acc1 = fmaf(xv, w.y, acc1);
            acc2 = fmaf(xv, w.z, acc2);
            acc3 = fmaf(xv, w.w, acc3);
        }
    }
    const int gr = row0 + r;
    if (gr < NN)
        *(float4*)&h1[gr * NH + og * 4] = make_float4(acc0, acc1, acc2, acc3);
}

// ---------------------------------------------------------------- CSR aggregation
// wave per node: lane = c + 16*g; 4 edges in parallel; shfl reduce over g.
// out[n][c] = ( sum_src hval(src,c)*dinv[src] + hval(n,c)*dinv[n] ) * dinv[n]
// RELU: hval(s,c) = relu(h[s][c] + b[c]) (layer-2 gather); else raw h.
template<bool RELU>
__global__ __launch_bounds__(256) void k_agg_csr(
    const int* __restrict__ row_start, const int* __restrict__ degi,
    const int* __restrict__ esrc_s, const float* __restrict__ dinv,
    const float* __restrict__ h, const float* __restrict__ b,
    float* __restrict__ outp) {
    const int node = blockIdx.x * 4 + (threadIdx.x >> 6);
    if (node >= NN) return;
    const int lane = threadIdx.x & 63;
    const int c = lane & 15;
    const int g = lane >> 4;
    const int beg = row_start[node];
    const int deg = degi[node];
    const float bc = RELU ? b[c] : 0.0f;

    float acc = 0.f;
    for (int e = beg + g; e < beg + deg; e += 4) {
        const int s = esrc_s[e];
        float hv = h[(size_t)s * NH + c];
        if (RELU) hv = fmaxf(hv + bc, 0.f);
        acc += hv * dinv[s];
    }
    acc += __shfl_xor(acc, 16);
    acc += __shfl_xor(acc, 32);

    if (g == 0) {
        const float dn = dinv[node];
        float hv = h[(size_t)node * NH + c];
        if (RELU) hv = fmaxf(hv + bc, 0.f);
        outp[(size_t)node * NH + c] = (acc + hv * dn) * dn;
    }
}

// ---------------------------------------------------------------- final: out = log_softmax(agg2 @ W2 + b2)
__global__ __launch_bounds__(256) void k_final(
    const float* __restrict__ agg2, const float* __restrict__ W2,
    const float* __restrict__ b2, float* __restrict__ out) {
    __shared__ float sW[NH * NC];
    __shared__ float sb[NC];
    const int t = threadIdx.x;
    for (int i = t; i < NH * NC; i += 256) sW[i] = W2[i];
    if (t < NC) sb[t] = b2[t];
    __syncthreads();

    const int row = blockIdx.x * blockDim.x + t;
    if (row >= NN) return;

    float h[NH];
    const float4* ap = (const float4*)&agg2[(size_t)row * NH];
    #pragma unroll
    for (int q = 0; q < 4; ++q) {
        const float4 a = ap[q];
        h[q * 4 + 0] = a.x; h[q * 4 + 1] = a.y; h[q * 4 + 2] = a.z; h[q * 4 + 3] = a.w;
    }
    float z[NC];
    #pragma unroll
    for (int c = 0; c < NC; ++c) z[c] = sb[c];
    #pragma unroll
    for (int k = 0; k < NH; ++k) {
        const float hv = h[k];
        #pragma unroll
        for (int c = 0; c < NC; ++c) z[c] = fmaf(hv, sW[k * NC + c], z[c]);
    }
    float m = z[0];
    #pragma unroll
    for (int c = 1; c < NC; ++c) m = fmaxf(m, z[c]);
    float sum = 0.f;
    #pragma unroll
    for (int c = 0; c < NC; ++c) sum += __expf(z[c] - m);
    const float lse = m + __logf(sum);
    #pragma unroll
    for (int c = 0; c < NC; ++c) out[(size_t)row * NC + c] = z[c] - lse;
}

// ---------------------------------------------------------------- launch
extern "C" void kernel_launch(void* const* d_in, const int* in_sizes, int n_in,
                              void* d_out, int out_size, void* d_ws, size_t ws_size,
                              hipStream_t stream) {
    const float* x  = (const float*)d_in[0];
    const int*   ei = (const int*)d_in[1];   // [2, NE] flat, int32 per harness
    const float* W1 = (const float*)d_in[2];
    const float* b1 = (const float*)d_in[3];
    const float* W2 = (const float*)d_in[4];
    const float* b2 = (const float*)d_in[5];
    float* out = (float*)d_out;

    // workspace layout (~33.6 MB)
    int* degi      = (int*)d_ws;            // NN
    int* row_start = degi + NN;              // NN
    int* cursor    = row_start + NN;         // NN
    int* part      = cursor + NN;            // 128
    int* esrc_s    = part + 128;             // NE
    float* dinv    = (float*)(esrc_s + NE);  // NN
    float* h1      = dinv + NN;              // NN*NH
    float* agg1    = h1 + NN * NH;           // NN*NH
    float* agg2    = agg1 + NN * NH;         // NN*NH

    const int* esrc = ei;
    const int* edst = ei + NE;

    const dim3 B(256);
    k_zero_deg  <<<(NN + 255) / 256, B, 0, stream>>>(degi);
    k_deg_count <<<(NE + 255) / 256, B, 0, stream>>>(edst, degi);
    k_dinv      <<<(NN + 255) / 256, B, 0, stream>>>(degi, dinv);
    k_chunk_sum <<<NCHUNK, B, 0, stream>>>(degi, part);
    k_scan_part <<<1, 128, 0, stream>>>(part);
    k_chunk_scan<<<NCHUNK, B, 0, stream>>>(degi, part, row_start, cursor);
    k_scatter   <<<(NE + 255) / 256, B, 0, stream>>>(esrc, edst, cursor, esrc_s);
    k_gemm1     <<<(NN + 63) / 64, B, 0, stream>>>(x, W1, h1);
    k_agg_csr<false><<<(NN + 3) / 4, B, 0, stream>>>(row_start, degi, esrc_s, dinv, h1, b1, agg1);
    k_agg_csr<true> <<<(NN + 3) / 4, B, 0, stream>>>(row_start, degi, esrc_s, dinv, agg1, b1, agg2);
    k_final     <<<(NN + 255) / 256, B, 0, stream>>>(agg2, W2, b2, out);
}

// Round 3
// 671.001 us; speedup vs baseline: 8.2186x; 1.0226x over previous
//
#include <hip/hip_runtime.h>
#include <math.h>

constexpr int NN = 100000;   // nodes
constexpr int NE = 3200000;  // edges
constexpr int DF = 512;      // in features
constexpr int NH = 16;       // hidden
constexpr int NC = 40;       // classes

constexpr int NB  = 512;     // buckets (grid = 2 blocks/CU exactly)
constexpr int BSZ = 196;     // nodes per bucket (512*196 = 100352 >= NN)
constexpr int CAP = 7168;    // per-bucket edge capacity (mean 6250, sd ~79 -> +11 sigma)
constexpr int SCHUNK = 16384;                       // edges per scatter block
constexpr int SGRID  = (NE + SCHUNK - 1) / SCHUNK;  // 196

// ---------------------------------------------------------------- init bucket cursors
__global__ void k_init(int* __restrict__ gcur) {
    int i = blockIdx.x * blockDim.x + threadIdx.x;
    if (i < NB) gcur[i] = i * CAP;
}

// ---------------------------------------------------------------- bucket counting-scatter
// pairs[pos] = src | (dst_local << 17); bucket = dst / BSZ
__global__ __launch_bounds__(1024) void k_scatter_bucket(
    const int* __restrict__ src, const int* __restrict__ dst,
    int* __restrict__ gcur, unsigned int* __restrict__ pairs) {
    __shared__ int hist[NB];
    __shared__ int gpos[NB];
    __shared__ int lcur[NB];
    const int t = threadIdx.x;
    for (int i = t; i < NB; i += 1024) { hist[i] = 0; lcur[i] = 0; }
    __syncthreads();

    const int base = blockIdx.x * SCHUNK;
    #pragma unroll
    for (int k = 0; k < SCHUNK / 1024; ++k) {
        const int i = base + k * 1024 + t;
        if (i < NE) atomicAdd(&hist[(unsigned)dst[i] / BSZ], 1);
    }
    __syncthreads();
    for (int i = t; i < NB; i += 1024)
        if (hist[i]) gpos[i] = atomicAdd(&gcur[i], hist[i]);
    __syncthreads();
    #pragma unroll
    for (int k = 0; k < SCHUNK / 1024; ++k) {
        const int i = base + k * 1024 + t;
        if (i < NE) {
            const unsigned d = (unsigned)dst[i];
            const unsigned b = d / BSZ;
            const unsigned dl = d - b * BSZ;
            const int off = atomicAdd(&lcur[b], 1);
            pairs[gpos[b] + off] = (unsigned)src[i] | (dl << 17);
        }
    }
}

// ---------------------------------------------------------------- per-node degree -> dinv
__global__ __launch_bounds__(256) void k_dinv_bucket(
    const unsigned int* __restrict__ pairs, const int* __restrict__ gcur,
    float* __restrict__ dinv) {
    __shared__ int hist[BSZ];
    const int b = blockIdx.x, t = threadIdx.x;
    if (t < BSZ) hist[t] = 0;
    __syncthreads();
    const int base = b * CAP;
    const int cnt  = gcur[b] - base;
    for (int p = base + t; p < base + cnt; p += 256)
        atomicAdd(&hist[pairs[p] >> 17], 1);
    __syncthreads();
    const int n = b * BSZ + t;
    if (t < BSZ && n < NN) dinv[n] = rsqrtf((float)(hist[t] + 1));
}

// ---------------------------------------------------------------- layer-1 GEMM: h1p = (x @ W1) * dinv[row]
__global__ __launch_bounds__(256) void k_gemm1(
    const float* __restrict__ x, const float* __restrict__ W1,
    const float* __restrict__ dinv, float* __restrict__ h1p) {
    __shared__ __align__(16) float sW[DF * NH];   // 32 KB
    __shared__ __align__(16) float sX[64][68];
    const int t = threadIdx.x;

    for (int i = t * 4; i < DF * NH; i += 256 * 4)
        *(float4*)&sW[i] = *(const float4*)&W1[i];

    const int row0 = blockIdx.x * 64;
    const int r  = t >> 2;
    const int og = t & 3;
    float acc0 = 0.f, acc1 = 0.f, acc2 = 0.f, acc3 = 0.f;

    for (int kc = 0; kc < DF; kc += 64) {
        __syncthreads();
        const int lc4 = t & 15;
        #pragma unroll
        for (int p = 0; p < 4; ++p) {
            const int lr = (t >> 4) + p * 16;
            const int gr = row0 + lr;
            float4 v = make_float4(0.f, 0.f, 0.f, 0.f);
            if (gr < NN) v = *(const float4*)&x[(size_t)gr * DF + kc + lc4 * 4];
            *(float4*)&sX[lr][lc4 * 4] = v;
        }
        __syncthreads();
        #pragma unroll 16
        for (int k = 0; k < 64; ++k) {
            const float xv = sX[r][k];
            const float4 w = *(const float4*)&sW[(kc + k) * NH + og * 4];
            acc0 = fmaf(xv, w.x, acc0);
            acc1 = fmaf(xv, w.y, acc1);
            acc2 = fmaf(xv, w.z, acc2);
            acc3 = fmaf(xv, w.w, acc3);
        }
    }
    const int gr = row0 + r;
    if (gr < NN) {
        const float s = dinv[gr];
        *(float4*)&h1p[gr * NH + og * 4] =
            make_float4(acc0 * s, acc1 * s, acc2 * s, acc3 * s);
    }
}

// ---------------------------------------------------------------- agg layer 1
// acc[c][dl] += h1p[src][c]; out A1[n][c] = relu((acc + h1p[n][c])*dinv[n] + b1[c]) * dinv[n]
__global__ __launch_bounds__(1024) void k_agg1(
    const unsigned int* __restrict__ pairs, const int* __restrict__ gcur,
    const float* __restrict__ h1p, const float* __restrict__ dinv,
    const float* __restrict__ b1, float* __restrict__ A1) {
    __shared__ float acc[NH * BSZ];  // 12.25 KB, column-major acc[c*BSZ+dl]
    const int b = blockIdx.x, t = threadIdx.x;
    for (int i = t; i < NH * BSZ; i += 1024) acc[i] = 0.f;
    __syncthreads();

    const int base = b * CAP;
    const int cnt  = gcur[b] - base;
    for (int p = base + t; p < base + cnt; p += 1024) {
        const unsigned u = pairs[p];
        const int s  = u & 0x1FFFF;
        const int dl = u >> 17;
        const float4* hp = (const float4*)&h1p[(size_t)s * NH];
        const float4 v0 = hp[0], v1 = hp[1], v2 = hp[2], v3 = hp[3];
        atomicAdd(&acc[ 0 * BSZ + dl], v0.x);
        atomicAdd(&acc[ 1 * BSZ + dl], v0.y);
        atomicAdd(&acc[ 2 * BSZ + dl], v0.z);
        atomicAdd(&acc[ 3 * BSZ + dl], v0.w);
        atomicAdd(&acc[ 4 * BSZ + dl], v1.x);
        atomicAdd(&acc[ 5 * BSZ + dl], v1.y);
        atomicAdd(&acc[ 6 * BSZ + dl], v1.z);
        atomicAdd(&acc[ 7 * BSZ + dl], v1.w);
        atomicAdd(&acc[ 8 * BSZ + dl], v2.x);
        atomicAdd(&acc[ 9 * BSZ + dl], v2.y);
        atomicAdd(&acc[10 * BSZ + dl], v2.z);
        atomicAdd(&acc[11 * BSZ + dl], v2.w);
        atomicAdd(&acc[12 * BSZ + dl], v3.x);
        atomicAdd(&acc[13 * BSZ + dl], v3.y);
        atomicAdd(&acc[14 * BSZ + dl], v3.z);
        atomicAdd(&acc[15 * BSZ + dl], v3.w);
    }
    __syncthreads();

    for (int j = t; j < BSZ * NH; j += 1024) {
        const int i = j >> 4, c = j & 15;
        const int n = b * BSZ + i;
        if (n < NN) {
            const float dn = dinv[n];
            const float pre = (acc[c * BSZ + i] + h1p[(size_t)n * NH + c]) * dn + b1[c];
            A1[(size_t)n * NH + c] = fmaxf(pre, 0.f) * dn;
        }
    }
}

// ---------------------------------------------------------------- agg layer 2 + W2 + log_softmax
__global__ __launch_bounds__(1024) void k_agg2_final(
    const unsigned int* __restrict__ pairs, const int* __restrict__ gcur,
    const float* __restrict__ A1, const float* __restrict__ dinv,
    const float* __restrict__ W2, const float* __restrict__ b2,
    float* __restrict__ out) {
    __shared__ float acc[NH * BSZ];
    __shared__ float sW2[NH * NC];
    __shared__ float sb2[NC];
    const int b = blockIdx.x, t = threadIdx.x;
    for (int i = t; i < NH * BSZ; i += 1024) acc[i] = 0.f;
    if (t < NH * NC) sW2[t] = W2[t];
    if (t >= 1024 - NC) sb2[t - (1024 - NC)] = b2[t - (1024 - NC)];
    __syncthreads();

    const int base = b * CAP;
    const int cnt  = gcur[b] - base;
    for (int p = base + t; p < base + cnt; p += 1024) {
        const unsigned u = pairs[p];
        const int s  = u & 0x1FFFF;
        const int dl = u >> 17;
        const float4* hp = (const float4*)&A1[(size_t)s * NH];
        const float4 v0 = hp[0], v1 = hp[1], v2 = hp[2], v3 = hp[3];
        atomicAdd(&acc[ 0 * BSZ + dl], v0.x);
        atomicAdd(&acc[ 1 * BSZ + dl], v0.y);
        atomicAdd(&acc[ 2 * BSZ + dl], v0.z);
        atomicAdd(&acc[ 3 * BSZ + dl], v0.w);
        atomicAdd(&acc[ 4 * BSZ + dl], v1.x);
        atomicAdd(&acc[ 5 * BSZ + dl], v1.y);
        atomicAdd(&acc[ 6 * BSZ + dl], v1.z);
        atomicAdd(&acc[ 7 * BSZ + dl], v1.w);
        atomicAdd(&acc[ 8 * BSZ + dl], v2.x);
        atomicAdd(&acc[ 9 * BSZ + dl], v2.y);
        atomicAdd(&acc[10 * BSZ + dl], v2.z);
        atomicAdd(&acc[11 * BSZ + dl], v2.w);
        atomicAdd(&acc[12 * BSZ + dl], v3.x);
        atomicAdd(&acc[13 * BSZ + dl], v3.y);
        atomicAdd(&acc[14 * BSZ + dl], v3.z);
        atomicAdd(&acc[15 * BSZ + dl], v3.w);
    }
    __syncthreads();

    // epilogue: 4 threads per node, 10 classes each
    if (t < BSZ * 4) {
        const int i = t >> 2, q = t & 3;
        const int n = b * BSZ + i;
        if (n < NN) {
            const float dn = dinv[n];
            float ag[NH];
            #pragma unroll
            for (int c = 0; c < NH; ++c)
                ag[c] = (acc[c * BSZ + i] + A1[(size_t)n * NH + c]) * dn;
            float z[10];
            #pragma unroll
            for (int cc = 0; cc < 10; ++cc) {
                const int col = q * 10 + cc;
                float zz = sb2[col];
                #pragma unroll
                for (int k = 0; k < NH; ++k) zz = fmaf(ag[k], sW2[k * NC + col], zz);
                z[cc] = zz;
            }
            float m = z[0];
            #pragma unroll
            for (int cc = 1; cc < 10; ++cc) m = fmaxf(m, z[cc]);
            m = fmaxf(m, __shfl_xor(m, 1));
            m = fmaxf(m, __shfl_xor(m, 2));
            float sum = 0.f;
            #pragma unroll
            for (int cc = 0; cc < 10; ++cc) sum += __expf(z[cc] - m);
            sum += __shfl_xor(sum, 1);
            sum += __shfl_xor(sum, 2);
            const float lse = m + __logf(sum);
            #pragma unroll
            for (int cc = 0; cc < 10; ++cc)
                out[(size_t)n * NC + q * 10 + cc] = z[cc] - lse;
        }
    }
}

// ---------------------------------------------------------------- launch
extern "C" void kernel_launch(void* const* d_in, const int* in_sizes, int n_in,
                              void* d_out, int out_size, void* d_ws, size_t ws_size,
                              hipStream_t stream) {
    const float* x  = (const float*)d_in[0];
    const int*   ei = (const int*)d_in[1];   // [2, NE] flat int32
    const float* W1 = (const float*)d_in[2];
    const float* b1 = (const float*)d_in[3];
    const float* W2 = (const float*)d_in[4];
    const float* b2 = (const float*)d_in[5];
    float* out = (float*)d_out;

    // workspace (~28 MB)
    int* gcur            = (int*)d_ws;                  // NB
    unsigned int* pairs  = (unsigned int*)(gcur + NB);  // NB*CAP
    float* dinv          = (float*)(pairs + (size_t)NB * CAP);  // NN
    float* h1p           = dinv + NN;                   // NN*NH
    float* A1            = h1p + (size_t)NN * NH;       // NN*NH

    const int* esrc = ei;
    const int* edst = ei + NE;

    k_init          <<<(NB + 255) / 256, 256, 0, stream>>>(gcur);
    k_scatter_bucket<<<SGRID, 1024, 0, stream>>>(esrc, edst, gcur, pairs);
    k_dinv_bucket   <<<NB, 256, 0, stream>>>(pairs, gcur, dinv);
    k_gemm1         <<<(NN + 63) / 64, 256, 0, stream>>>(x, W1, dinv, h1p);
    k_agg1          <<<NB, 1024, 0, stream>>>(pairs, gcur, h1p, dinv, b1, A1);
    k_agg2_final    <<<NB, 1024, 0, stream>>>(pairs, gcur, A1, dinv, W2, b2, out);
}

// Round 4
// 669.787 us; speedup vs baseline: 8.2335x; 1.0018x over previous
//
#include <hip/hip_runtime.h>
#include <math.h>

typedef unsigned int u32;

constexpr int NN = 100000;   // nodes
constexpr int NE = 3200000;  // edges
constexpr int DF = 512;      // in features
constexpr int NH = 16;       // hidden
constexpr int NC = 40;       // classes

constexpr int NB  = 512;     // buckets (grid = 2 blocks/CU exactly)
constexpr int BSZ = 196;     // nodes per bucket (512*196 >= NN)
constexpr int CAP = 7168;    // per-bucket edge capacity (mean 6250)
constexpr int SCHUNK = 16384;
constexpr int SGRID  = (NE + SCHUNK - 1) / SCHUNK;

// ---------------------------------------------------------------- bf16 pack helpers
__device__ __forceinline__ u32 pack_bf2(float lo, float hi) {
    u32 a = __float_as_uint(lo), b = __float_as_uint(hi);
    a += 0x7FFFu + ((a >> 16) & 1u);   // RNE
    b += 0x7FFFu + ((b >> 16) & 1u);
    return (a >> 16) | (b & 0xFFFF0000u);
}
__device__ __forceinline__ float bf_lo(u32 u) { return __uint_as_float(u << 16); }
__device__ __forceinline__ float bf_hi(u32 u) { return __uint_as_float(u & 0xFFFF0000u); }

// ---------------------------------------------------------------- init bucket cursors
__global__ void k_init(int* __restrict__ gcur) {
    int i = blockIdx.x * blockDim.x + threadIdx.x;
    if (i < NB) gcur[i] = i * CAP;
}

// ---------------------------------------------------------------- bucket counting-scatter
__global__ __launch_bounds__(1024) void k_scatter_bucket(
    const int* __restrict__ src, const int* __restrict__ dst,
    int* __restrict__ gcur, u32* __restrict__ pairs) {
    __shared__ int hist[NB];
    __shared__ int gpos[NB];
    __shared__ int lcur[NB];
    const int t = threadIdx.x;
    for (int i = t; i < NB; i += 1024) { hist[i] = 0; lcur[i] = 0; }
    __syncthreads();

    const int base = blockIdx.x * SCHUNK;
    #pragma unroll
    for (int k = 0; k < SCHUNK / 1024; ++k) {
        const int i = base + k * 1024 + t;
        if (i < NE) atomicAdd(&hist[(unsigned)dst[i] / BSZ], 1);
    }
    __syncthreads();
    for (int i = t; i < NB; i += 1024)
        if (hist[i]) gpos[i] = atomicAdd(&gcur[i], hist[i]);
    __syncthreads();
    #pragma unroll
    for (int k = 0; k < SCHUNK / 1024; ++k) {
        const int i = base + k * 1024 + t;
        if (i < NE) {
            const unsigned d = (unsigned)dst[i];
            const unsigned b = d / BSZ;
            const unsigned dl = d - b * BSZ;
            const int off = atomicAdd(&lcur[b], 1);
            pairs[gpos[b] + off] = (unsigned)src[i] | (dl << 17);
        }
    }
}

// ---------------------------------------------------------------- per-node degree -> dinv
__global__ __launch_bounds__(256) void k_dinv_bucket(
    const u32* __restrict__ pairs, const int* __restrict__ gcur,
    float* __restrict__ dinv) {
    __shared__ int hist[BSZ];
    const int b = blockIdx.x, t = threadIdx.x;
    if (t < BSZ) hist[t] = 0;
    __syncthreads();
    const int base = b * CAP;
    const int cnt  = gcur[b] - base;
    for (int p = base + t; p < base + cnt; p += 256)
        atomicAdd(&hist[pairs[p] >> 17], 1);
    __syncthreads();
    const int n = b * BSZ + t;
    if (t < BSZ && n < NN) dinv[n] = rsqrtf((float)(hist[t] + 1));
}

// ---------------------------------------------------------------- layer-1 GEMM
// h1b[n] = bf16x16 row of (x[n] @ W1) * dinv[n]
__global__ __launch_bounds__(256) void k_gemm1(
    const float* __restrict__ x, const float* __restrict__ W1,
    const float* __restrict__ dinv, u32* __restrict__ h1b) {
    __shared__ __align__(16) float sW[DF * NH];   // 32 KB
    __shared__ __align__(16) float sX[64][68];
    const int t = threadIdx.x;

    for (int i = t * 4; i < DF * NH; i += 256 * 4)
        *(float4*)&sW[i] = *(const float4*)&W1[i];

    const int row0 = blockIdx.x * 64;
    const int r  = t >> 2;
    const int og = t & 3;
    float acc0 = 0.f, acc1 = 0.f, acc2 = 0.f, acc3 = 0.f;

    for (int kc = 0; kc < DF; kc += 64) {
        __syncthreads();
        const int lc4 = t & 15;
        #pragma unroll
        for (int p = 0; p < 4; ++p) {
            const int lr = (t >> 4) + p * 16;
            const int gr = row0 + lr;
            float4 v = make_float4(0.f, 0.f, 0.f, 0.f);
            if (gr < NN) v = *(const float4*)&x[(size_t)gr * DF + kc + lc4 * 4];
            *(float4*)&sX[lr][lc4 * 4] = v;
        }
        __syncthreads();
        #pragma unroll 16
        for (int k = 0; k < 64; ++k) {
            const float xv = sX[r][k];
            const float4 w = *(const float4*)&sW[(kc + k) * NH + og * 4];
            acc0 = fmaf(xv, w.x, acc0);
            acc1 = fmaf(xv, w.y, acc1);
            acc2 = fmaf(xv, w.z, acc2);
            acc3 = fmaf(xv, w.w, acc3);
        }
    }
    const int gr = row0 + r;
    if (gr < NN) {
        const float s = dinv[gr];
        const u32 w0 = pack_bf2(acc0 * s, acc1 * s);
        const u32 w1 = pack_bf2(acc2 * s, acc3 * s);
        *(uint2*)&h1b[(size_t)gr * 8 + og * 2] = make_uint2(w0, w1);
    }
}

// 16 LDS atomic adds of one bf16x16 row (2 uint4) into column-major acc
#define ACC16(A, B, DL)                                                    \
    {   u32 ww[8] = {(A).x, (A).y, (A).z, (A).w, (B).x, (B).y, (B).z, (B).w}; \
        _Pragma("unroll")                                                  \
        for (int q = 0; q < 8; ++q) {                                      \
            atomicAdd(&acc[(2 * q)     * BSZ + (DL)], bf_lo(ww[q]));       \
            atomicAdd(&acc[(2 * q + 1) * BSZ + (DL)], bf_hi(ww[q]));       \
        } }

// ---------------------------------------------------------------- agg layer 1
// A1[n] = bf16( relu( (sum_src h1b[src] + h1b[n]) * dinv[n] + b1 ) * dinv[n] )
__global__ __launch_bounds__(1024, 8) void k_agg1(
    const u32* __restrict__ pairs, const int* __restrict__ gcur,
    const u32* __restrict__ h1b, const float* __restrict__ dinv,
    const float* __restrict__ b1, u32* __restrict__ A1) {
    __shared__ float acc[NH * BSZ];  // 12.25 KB column-major
    const int b = blockIdx.x, t = threadIdx.x;
    for (int i = t; i < NH * BSZ; i += 1024) acc[i] = 0.f;
    __syncthreads();

    const int base = b * CAP;
    const int end  = gcur[b];
    for (int p = base + t; p < end; p += 2048) {
        const int p2 = p + 1024;
        const u32 u0 = pairs[p];
        const bool v1 = (p2 < end);
        const u32 u1 = v1 ? pairs[p2] : 0u;
        const uint4* r0 = (const uint4*)&h1b[(size_t)(u0 & 0x1FFFFu) * 8];
        const uint4 a0 = r0[0], b0 = r0[1];
        uint4 a1, b1v;
        if (v1) {
            const uint4* r1 = (const uint4*)&h1b[(size_t)(u1 & 0x1FFFFu) * 8];
            a1 = r1[0]; b1v = r1[1];
        }
        { const int dl = u0 >> 17; ACC16(a0, b0, dl); }
        if (v1) { const int dl = u1 >> 17; ACC16(a1, b1v, dl); }
    }
    __syncthreads();

    if (t < BSZ) {
        const int n = b * BSZ + t;
        if (n < NN) {
            const float dn = dinv[n];
            const uint4* hp = (const uint4*)&h1b[(size_t)n * 8];
            const uint4 ha = hp[0], hbv = hp[1];
            const u32 ws_[8] = {ha.x, ha.y, ha.z, ha.w, hbv.x, hbv.y, hbv.z, hbv.w};
            u32 ow[8];
            #pragma unroll
            for (int q = 0; q < 8; ++q) {
                const float p0 = (acc[(2*q)   * BSZ + t] + bf_lo(ws_[q])) * dn + b1[2*q];
                const float p1 = (acc[(2*q+1) * BSZ + t] + bf_hi(ws_[q])) * dn + b1[2*q+1];
                ow[q] = pack_bf2(fmaxf(p0, 0.f) * dn, fmaxf(p1, 0.f) * dn);
            }
            uint4* op = (uint4*)&A1[(size_t)n * 8];
            op[0] = make_uint4(ow[0], ow[1], ow[2], ow[3]);
            op[1] = make_uint4(ow[4], ow[5], ow[6], ow[7]);
        }
    }
}

// ---------------------------------------------------------------- agg layer 2 + W2 + log_softmax
__global__ __launch_bounds__(1024, 8) void k_agg2_final(
    const u32* __restrict__ pairs, const int* __restrict__ gcur,
    const u32* __restrict__ A1, const float* __restrict__ dinv,
    const float* __restrict__ W2, const float* __restrict__ b2,
    float* __restrict__ out) {
    __shared__ float acc[NH * BSZ];
    __shared__ float sW2[NH * NC];
    __shared__ float sb2[NC];
    const int b = blockIdx.x, t = threadIdx.x;
    for (int i = t; i < NH * BSZ; i += 1024) acc[i] = 0.f;
    if (t < NH * NC) sW2[t] = W2[t];
    if (t < NC) sb2[t] = b2[t];
    __syncthreads();

    const int base = b * CAP;
    const int end  = gcur[b];
    for (int p = base + t; p < end; p += 2048) {
        const int p2 = p + 1024;
        const u32 u0 = pairs[p];
        const bool v1 = (p2 < end);
        const u32 u1 = v1 ? pairs[p2] : 0u;
        const uint4* r0 = (const uint4*)&A1[(size_t)(u0 & 0x1FFFFu) * 8];
        const uint4 a0 = r0[0], b0 = r0[1];
        uint4 a1, b1v;
        if (v1) {
            const uint4* r1 = (const uint4*)&A1[(size_t)(u1 & 0x1FFFFu) * 8];
            a1 = r1[0]; b1v = r1[1];
        }
        { const int dl = u0 >> 17; ACC16(a0, b0, dl); }
        if (v1) { const int dl = u1 >> 17; ACC16(a1, b1v, dl); }
    }
    __syncthreads();

    // epilogue: 4 threads per node, 10 classes each
    if (t < BSZ * 4) {
        const int i = t >> 2, q = t & 3;
        const int n = b * BSZ + i;
        if (n < NN) {
            const float dn = dinv[n];
            const uint4* hp = (const uint4*)&A1[(size_t)n * 8];
            const uint4 ha = hp[0], hbv = hp[1];
            const u32 ws_[8] = {ha.x, ha.y, ha.z, ha.w, hbv.x, hbv.y, hbv.z, hbv.w};
            float ag[NH];
            #pragma unroll
            for (int qq = 0; qq < 8; ++qq) {
                ag[2*qq]   = (acc[(2*qq)   * BSZ + i] + bf_lo(ws_[qq])) * dn;
                ag[2*qq+1] = (acc[(2*qq+1) * BSZ + i] + bf_hi(ws_[qq])) * dn;
            }
            float z[10];
            #pragma unroll
            for (int cc = 0; cc < 10; ++cc) {
                const int col = q * 10 + cc;
                float zz = sb2[col];
                #pragma unroll
                for (int k = 0; k < NH; ++k) zz = fmaf(ag[k], sW2[k * NC + col], zz);
                z[cc] = zz;
            }
            float m = z[0];
            #pragma unroll
            for (int cc = 1; cc < 10; ++cc) m = fmaxf(m, z[cc]);
            m = fmaxf(m, __shfl_xor(m, 1));
            m = fmaxf(m, __shfl_xor(m, 2));
            float sum = 0.f;
            #pragma unroll
            for (int cc = 0; cc < 10; ++cc) sum += __expf(z[cc] - m);
            sum += __shfl_xor(sum, 1);
            sum += __shfl_xor(sum, 2);
            const float lse = m + __logf(sum);
            #pragma unroll
            for (int cc = 0; cc < 10; ++cc)
                out[(size_t)n * NC + q * 10 + cc] = z[cc] - lse;
        }
    }
}

// ---------------------------------------------------------------- launch
extern "C" void kernel_launch(void* const* d_in, const int* in_sizes, int n_in,
                              void* d_out, int out_size, void* d_ws, size_t ws_size,
                              hipStream_t stream) {
    const float* x  = (const float*)d_in[0];
    const int*   ei = (const int*)d_in[1];   // [2, NE] flat int32
    const float* W1 = (const float*)d_in[2];
    const float* b1 = (const float*)d_in[3];
    const float* W2 = (const float*)d_in[4];
    const float* b2 = (const float*)d_in[5];
    float* out = (float*)d_out;

    // workspace (~21.5 MB)
    int* gcur   = (int*)d_ws;                           // NB
    u32* pairs  = (u32*)(gcur + NB);                    // NB*CAP
    float* dinv = (float*)(pairs + (size_t)NB * CAP);   // NN
    u32* h1b    = (u32*)(dinv + NN);                    // NN*8 (bf16x16 rows)
    u32* A1     = h1b + (size_t)NN * 8;                 // NN*8

    const int* esrc = ei;
    const int* edst = ei + NE;

    k_init          <<<(NB + 255) / 256, 256, 0, stream>>>(gcur);
    k_scatter_bucket<<<SGRID, 1024, 0, stream>>>(esrc, edst, gcur, pairs);
    k_dinv_bucket   <<<NB, 256, 0, stream>>>(pairs, gcur, dinv);
    k_gemm1         <<<(NN + 63) / 64, 256, 0, stream>>>(x, W1, dinv, h1b);
    k_agg1          <<<NB, 1024, 0, stream>>>(pairs, gcur, h1b, dinv, b1, A1);
    k_agg2_final    <<<NB, 1024, 0, stream>>>(pairs, gcur, A1, dinv, W2, b2, out);
}

// Round 5
// 255.960 us; speedup vs baseline: 21.5452x; 2.6168x over previous
//
#include <hip/hip_runtime.h>
#include <math.h>

typedef unsigned int u32;

constexpr int NN = 100000;   // nodes
constexpr int NE = 3200000;  // edges
constexpr int DF = 512;      // in features
constexpr int NH = 16;       // hidden
constexpr int NC = 40;       // classes

constexpr int NB  = 512;     // buckets
constexpr int BSZ = 196;     // nodes per bucket (512*196 >= NN)
constexpr int CAP = 7168;    // per-bucket edge capacity (mean 6250)
constexpr int SCHUNK = 16384;
constexpr int SGRID  = (NE + SCHUNK - 1) / SCHUNK;

// ---------------------------------------------------------------- bf16 helpers
__device__ __forceinline__ u32 pack_bf2(float lo, float hi) {
    u32 a = __float_as_uint(lo), b = __float_as_uint(hi);
    a += 0x7FFFu + ((a >> 16) & 1u);   // RNE
    b += 0x7FFFu + ((b >> 16) & 1u);
    return (a >> 16) | (b & 0xFFFF0000u);
}
__device__ __forceinline__ float bf_lo(u32 u) { return __uint_as_float(u << 16); }
__device__ __forceinline__ float bf_hi(u32 u) { return __uint_as_float(u & 0xFFFF0000u); }

// ---------------------------------------------------------------- init bucket cursors
__global__ void k_init(int* __restrict__ gcur) {
    int i = blockIdx.x * blockDim.x + threadIdx.x;
    if (i < NB) gcur[i] = i * CAP;
}

// ---------------------------------------------------------------- bucket counting-scatter
__global__ __launch_bounds__(1024) void k_scatter_bucket(
    const int* __restrict__ src, const int* __restrict__ dst,
    int* __restrict__ gcur, u32* __restrict__ pairs) {
    __shared__ int hist[NB];
    __shared__ int gpos[NB];
    __shared__ int lcur[NB];
    const int t = threadIdx.x;
    for (int i = t; i < NB; i += 1024) { hist[i] = 0; lcur[i] = 0; }
    __syncthreads();

    const int base = blockIdx.x * SCHUNK;
    #pragma unroll
    for (int k = 0; k < SCHUNK / 1024; ++k) {
        const int i = base + k * 1024 + t;
        if (i < NE) atomicAdd(&hist[(unsigned)dst[i] / BSZ], 1);
    }
    __syncthreads();
    for (int i = t; i < NB; i += 1024)
        if (hist[i]) gpos[i] = atomicAdd(&gcur[i], hist[i]);
    __syncthreads();
    #pragma unroll
    for (int k = 0; k < SCHUNK / 1024; ++k) {
        const int i = base + k * 1024 + t;
        if (i < NE) {
            const unsigned d = (unsigned)dst[i];
            const unsigned b = d / BSZ;
            const unsigned dl = d - b * BSZ;
            const int off = atomicAdd(&lcur[b], 1);
            pairs[gpos[b] + off] = (unsigned)src[i] | (dl << 17);
        }
    }
}

// ---------------------------------------------------------------- per-bucket counting sort by dl
// produces dst-sorted esrc_s + row_start/degs/dinv
__global__ __launch_bounds__(1024) void k_sort_bucket(
    const u32* __restrict__ pairs, const int* __restrict__ gcur,
    int* __restrict__ esrc_s, int* __restrict__ row_start,
    int* __restrict__ degs, float* __restrict__ dinv) {
    __shared__ int hist[BSZ];
    __shared__ int scan[256];
    __shared__ int cur[BSZ];
    const int b = blockIdx.x, t = threadIdx.x;
    if (t < BSZ) hist[t] = 0;
    __syncthreads();

    const int base = b * CAP;
    const int end  = gcur[b];
    for (int p = base + t; p < end; p += 1024)
        atomicAdd(&hist[pairs[p] >> 17], 1);
    __syncthreads();

    const int h = (t < BSZ) ? hist[t] : 0;
    if (t < 256) scan[t] = (t < BSZ) ? h : 0;
    __syncthreads();
    #pragma unroll
    for (int off = 1; off < 256; off <<= 1) {
        int u = 0;
        if (t < 256 && t >= off) u = scan[t - off];
        __syncthreads();
        if (t < 256) scan[t] += u;
        __syncthreads();
    }
    if (t < BSZ) {
        const int st = scan[t] - h;   // exclusive
        cur[t] = st;
        const int n = b * BSZ + t;
        if (n < NN) {
            row_start[n] = base + st;
            degs[n] = h;
            dinv[n] = rsqrtf((float)(h + 1));
        }
    }
    __syncthreads();
    for (int p = base + t; p < end; p += 1024) {
        const u32 u = pairs[p];
        const int dl = u >> 17;
        const int pos = atomicAdd(&cur[dl], 1);
        esrc_s[base + pos] = (int)(u & 0x1FFFFu);
    }
}

// ---------------------------------------------------------------- layer-1 GEMM
// h1b[n] = bf16x16 row of (x[n] @ W1) * dinv[n]
__global__ __launch_bounds__(256) void k_gemm1(
    const float* __restrict__ x, const float* __restrict__ W1,
    const float* __restrict__ dinv, u32* __restrict__ h1b) {
    __shared__ __align__(16) float sW[DF * NH];   // 32 KB
    __shared__ __align__(16) float sX[64][68];
    const int t = threadIdx.x;

    for (int i = t * 4; i < DF * NH; i += 256 * 4)
        *(float4*)&sW[i] = *(const float4*)&W1[i];

    const int row0 = blockIdx.x * 64;
    const int r  = t >> 2;
    const int og = t & 3;
    float acc0 = 0.f, acc1 = 0.f, acc2 = 0.f, acc3 = 0.f;

    for (int kc = 0; kc < DF; kc += 64) {
        __syncthreads();
        const int lc4 = t & 15;
        #pragma unroll
        for (int p = 0; p < 4; ++p) {
            const int lr = (t >> 4) + p * 16;
            const int gr = row0 + lr;
            float4 v = make_float4(0.f, 0.f, 0.f, 0.f);
            if (gr < NN) v = *(const float4*)&x[(size_t)gr * DF + kc + lc4 * 4];
            *(float4*)&sX[lr][lc4 * 4] = v;
        }
        __syncthreads();
        #pragma unroll 16
        for (int k = 0; k < 64; ++k) {
            const float xv = sX[r][k];
            const float4 w = *(const float4*)&sW[(kc + k) * NH + og * 4];
            acc0 = fmaf(xv, w.x, acc0);
            acc1 = fmaf(xv, w.y, acc1);
            acc2 = fmaf(xv, w.z, acc2);
            acc3 = fmaf(xv, w.w, acc3);
        }
    }
    const int gr = row0 + r;
    if (gr < NN) {
        const float s = dinv[gr];
        const u32 w0 = pack_bf2(acc0 * s, acc1 * s);
        const u32 w1 = pack_bf2(acc2 * s, acc3 * s);
        *(uint2*)&h1b[(size_t)gr * 8 + og * 2] = make_uint2(w0, w1);
    }
}

// ---------------------------------------------------------------- CSR gather agg, layer 1
// wave per node: lane = l (u32 col 0..7) + 8*g (edge group 0..7)
// A1[n] = bf16( relu( (sum_src h1b[src] + h1b[n])*dn + b1 ) * dn )
__global__ __launch_bounds__(1024) void k_agg1(
    const int* __restrict__ row_start, const int* __restrict__ degs,
    const int* __restrict__ esrc_s, const u32* __restrict__ h1b,
    const float* __restrict__ dinv, const float* __restrict__ b1,
    u32* __restrict__ A1) {
    const int node = blockIdx.x * 16 + (threadIdx.x >> 6);
    if (node >= NN) return;
    const int lane = threadIdx.x & 63;
    const int l = lane & 7;
    const int g = lane >> 3;
    const int beg = row_start[node];
    const int end = beg + degs[node];

    float a0 = 0.f, a1 = 0.f;
    int e = beg + g;
    for (; e + 8 < end; e += 16) {
        const int s0 = esrc_s[e];
        const int s1 = esrc_s[e + 8];
        const u32 u0 = h1b[(size_t)s0 * 8 + l];
        const u32 u1 = h1b[(size_t)s1 * 8 + l];
        a0 += bf_lo(u0); a1 += bf_hi(u0);
        a0 += bf_lo(u1); a1 += bf_hi(u1);
    }
    if (e < end) {
        const u32 u0 = h1b[(size_t)esrc_s[e] * 8 + l];
        a0 += bf_lo(u0); a1 += bf_hi(u0);
    }
    a0 += __shfl_xor(a0, 8);  a1 += __shfl_xor(a1, 8);
    a0 += __shfl_xor(a0, 16); a1 += __shfl_xor(a1, 16);
    a0 += __shfl_xor(a0, 32); a1 += __shfl_xor(a1, 32);

    if (g == 0) {
        const float dn = dinv[node];
        const u32 su = h1b[(size_t)node * 8 + l];
        const float p0 = (a0 + bf_lo(su)) * dn + b1[2 * l];
        const float p1 = (a1 + bf_hi(su)) * dn + b1[2 * l + 1];
        A1[(size_t)node * 8 + l] = pack_bf2(fmaxf(p0, 0.f) * dn, fmaxf(p1, 0.f) * dn);
    }
}

// ---------------------------------------------------------------- CSR gather agg, layer 2 + W2 + log_softmax
__global__ __launch_bounds__(1024) void k_agg2_final(
    const int* __restrict__ row_start, const int* __restrict__ degs,
    const int* __restrict__ esrc_s, const u32* __restrict__ A1,
    const float* __restrict__ dinv, const float* __restrict__ W2,
    const float* __restrict__ b2, float* __restrict__ out) {
    __shared__ float sW2[NH * NC];
    __shared__ float sb2[NC];
    const int t = threadIdx.x;
    if (t < NH * NC) sW2[t] = W2[t];
    if (t >= 1024 - NC) sb2[t - (1024 - NC)] = b2[t - (1024 - NC)];
    __syncthreads();

    const int node = blockIdx.x * 16 + (t >> 6);
    if (node >= NN) return;
    const int lane = t & 63;
    const int l = lane & 7;
    const int g = lane >> 3;
    const int beg = row_start[node];
    const int end = beg + degs[node];

    float a0 = 0.f, a1 = 0.f;
    int e = beg + g;
    for (; e + 8 < end; e += 16) {
        const int s0 = esrc_s[e];
        const int s1 = esrc_s[e + 8];
        const u32 u0 = A1[(size_t)s0 * 8 + l];
        const u32 u1 = A1[(size_t)s1 * 8 + l];
        a0 += bf_lo(u0); a1 += bf_hi(u0);
        a0 += bf_lo(u1); a1 += bf_hi(u1);
    }
    if (e < end) {
        const u32 u0 = A1[(size_t)esrc_s[e] * 8 + l];
        a0 += bf_lo(u0); a1 += bf_hi(u0);
    }
    a0 += __shfl_xor(a0, 8);  a1 += __shfl_xor(a1, 8);
    a0 += __shfl_xor(a0, 16); a1 += __shfl_xor(a1, 16);
    a0 += __shfl_xor(a0, 32); a1 += __shfl_xor(a1, 32);

    // every lane now holds sums for channels (2l, 2l+1)
    const float dn = dinv[node];
    const u32 su = A1[(size_t)node * 8 + l];
    const float ag0 = (a0 + bf_lo(su)) * dn;   // channel 2l
    const float ag1 = (a1 + bf_hi(su)) * dn;   // channel 2l+1

    float z = (lane < NC) ? sb2[lane] : -1e30f;
    #pragma unroll
    for (int k = 0; k < 8; ++k) {
        const float v0 = __shfl(ag0, k);   // channel 2k
        const float v1 = __shfl(ag1, k);   // channel 2k+1
        if (lane < NC) {
            z = fmaf(v0, sW2[(2 * k) * NC + lane], z);
            z = fmaf(v1, sW2[(2 * k + 1) * NC + lane], z);
        }
    }
    float m = z;
    #pragma unroll
    for (int off = 1; off < 64; off <<= 1) m = fmaxf(m, __shfl_xor(m, off));
    float sum = (lane < NC) ? __expf(z - m) : 0.f;
    #pragma unroll
    for (int off = 1; off < 64; off <<= 1) sum += __shfl_xor(sum, off);
    const float lse = m + __logf(sum);
    if (lane < NC) out[(size_t)node * NC + lane] = z - lse;
}

// ---------------------------------------------------------------- launch
extern "C" void kernel_launch(void* const* d_in, const int* in_sizes, int n_in,
                              void* d_out, int out_size, void* d_ws, size_t ws_size,
                              hipStream_t stream) {
    const float* x  = (const float*)d_in[0];
    const int*   ei = (const int*)d_in[1];   // [2, NE] flat int32
    const float* W1 = (const float*)d_in[2];
    const float* b1 = (const float*)d_in[3];
    const float* W2 = (const float*)d_in[4];
    const float* b2 = (const float*)d_in[5];
    float* out = (float*)d_out;

    // workspace (~37 MB)
    int* gcur      = (int*)d_ws;                           // NB
    u32* pairs     = (u32*)(gcur + NB);                    // NB*CAP
    int* esrc_s    = (int*)(pairs + (size_t)NB * CAP);     // NB*CAP
    int* row_start = esrc_s + (size_t)NB * CAP;            // NN
    int* degs      = row_start + NN;                       // NN
    float* dinv    = (float*)(degs + NN);                  // NN
    u32* h1b       = (u32*)(dinv + NN);                    // NN*8
    u32* A1        = h1b + (size_t)NN * 8;                 // NN*8

    const int* esrc = ei;
    const int* edst = ei + NE;

    k_init          <<<(NB + 255) / 256, 256, 0, stream>>>(gcur);
    k_scatter_bucket<<<SGRID, 1024, 0, stream>>>(esrc, edst, gcur, pairs);
    k_sort_bucket   <<<NB, 1024, 0, stream>>>(pairs, gcur, esrc_s, row_start, degs, dinv);
    k_gemm1         <<<(NN + 63) / 64, 256, 0, stream>>>(x, W1, dinv, h1b);
    k_agg1          <<<(NN + 15) / 16, 1024, 0, stream>>>(row_start, degs, esrc_s, h1b, dinv, b1, A1);
    k_agg2_final    <<<(NN + 15) / 16, 1024, 0, stream>>>(row_start, degs, esrc_s, A1, dinv, W2, b2, out);
}

// Round 6
// 226.355 us; speedup vs baseline: 24.3631x; 1.1308x over previous
//
#include <hip/hip_runtime.h>
#include <math.h>

typedef unsigned int u32;

constexpr int NN = 100000;   // nodes
constexpr int NE = 3200000;  // edges
constexpr int DF = 512;      // in features
constexpr int NH = 16;       // hidden
constexpr int NC = 40;       // classes

constexpr int NB  = 512;     // buckets
constexpr int BSZ = 196;     // nodes per bucket (512*196 >= NN)
constexpr int CAP = 7168;    // per-bucket edge capacity (mean 6250, +11 sigma)
constexpr int SCHUNK = 16384;
constexpr int SGRID  = (NE + SCHUNK - 1) / SCHUNK;

// ---------------------------------------------------------------- bf16 helpers
__device__ __forceinline__ u32 pack_bf2(float lo, float hi) {
    u32 a = __float_as_uint(lo), b = __float_as_uint(hi);
    a += 0x7FFFu + ((a >> 16) & 1u);   // RNE
    b += 0x7FFFu + ((b >> 16) & 1u);
    return (a >> 16) | (b & 0xFFFF0000u);
}
__device__ __forceinline__ float bf_lo(u32 u) { return __uint_as_float(u << 16); }
__device__ __forceinline__ float bf_hi(u32 u) { return __uint_as_float(u & 0xFFFF0000u); }

// ---------------------------------------------------------------- init bucket cursors
__global__ void k_init(int* __restrict__ gcur) {
    int i = blockIdx.x * blockDim.x + threadIdx.x;
    if (i < NB) gcur[i] = i * CAP;
}

// ---------------------------------------------------------------- bucket counting-scatter
__global__ __launch_bounds__(1024) void k_scatter_bucket(
    const int* __restrict__ src, const int* __restrict__ dst,
    int* __restrict__ gcur, u32* __restrict__ pairs) {
    __shared__ int hist[NB];
    __shared__ int gpos[NB];
    __shared__ int lcur[NB];
    const int t = threadIdx.x;
    for (int i = t; i < NB; i += 1024) { hist[i] = 0; lcur[i] = 0; }
    __syncthreads();

    const int base = blockIdx.x * SCHUNK;
    #pragma unroll
    for (int k = 0; k < SCHUNK / 1024; ++k) {
        const int i = base + k * 1024 + t;
        if (i < NE) atomicAdd(&hist[(unsigned)dst[i] / BSZ], 1);
    }
    __syncthreads();
    for (int i = t; i < NB; i += 1024)
        if (hist[i]) gpos[i] = atomicAdd(&gcur[i], hist[i]);
    __syncthreads();
    #pragma unroll
    for (int k = 0; k < SCHUNK / 1024; ++k) {
        const int i = base + k * 1024 + t;
        if (i < NE) {
            const unsigned d = (unsigned)dst[i];
            const unsigned b = d / BSZ;
            const unsigned dl = d - b * BSZ;
            const int off = atomicAdd(&lcur[b], 1);
            pairs[gpos[b] + off] = (unsigned)src[i] | (dl << 17);
        }
    }
}

// ---------------------------------------------------------------- per-bucket counting sort by dl
__global__ __launch_bounds__(1024) void k_sort_bucket(
    const u32* __restrict__ pairs, const int* __restrict__ gcur,
    int* __restrict__ esrc_s, int* __restrict__ row_start,
    int* __restrict__ degs, float* __restrict__ dinv) {
    __shared__ int hist[BSZ];
    __shared__ int scan[256];
    __shared__ int cur[BSZ];
    const int b = blockIdx.x, t = threadIdx.x;
    if (t < BSZ) hist[t] = 0;
    __syncthreads();

    const int base = b * CAP;
    const int end  = gcur[b];
    for (int p = base + t; p < end; p += 1024)
        atomicAdd(&hist[pairs[p] >> 17], 1);
    __syncthreads();

    const int h = (t < BSZ) ? hist[t] : 0;
    if (t < 256) scan[t] = (t < BSZ) ? h : 0;
    __syncthreads();
    #pragma unroll
    for (int off = 1; off < 256; off <<= 1) {
        int u = 0;
        if (t < 256 && t >= off) u = scan[t - off];
        __syncthreads();
        if (t < 256) scan[t] += u;
        __syncthreads();
    }
    if (t < BSZ) {
        const int st = scan[t] - h;   // exclusive
        cur[t] = st;
        const int n = b * BSZ + t;
        if (n < NN) {
            row_start[n] = base + st;
            degs[n] = h;
            dinv[n] = rsqrtf((float)(h + 1));
        }
    }
    __syncthreads();
    for (int p = base + t; p < end; p += 1024) {
        const u32 u = pairs[p];
        const int dl = u >> 17;
        const int pos = atomicAdd(&cur[dl], 1);
        esrc_s[base + pos] = (int)(u & 0x1FFFFu);
    }
}

// ---------------------------------------------------------------- layer-1 GEMM
// h1b[n] = bf16x16 row of (x[n] @ W1) * dinv[n]
// wave w of 4: cols 4w..4w+3 for all 64 rows; W1 read wave-uniform (scalar path);
// x tile in LDS stride-65 (conflict-free); register-prefetch double buffer.
__global__ __launch_bounds__(256) void k_gemm1(
    const float* __restrict__ x, const float* __restrict__ W1,
    const float* __restrict__ dinv, u32* __restrict__ h1b) {
    __shared__ float sX[64 * 65];   // 16.6 KB
    const int t    = threadIdx.x;
    const int lane = t & 63;
    const int og   = __builtin_amdgcn_readfirstlane(t >> 6);  // wave id, SGPR

    const int row0 = blockIdx.x * 64;
    // loader mapping: lr = t>>2 (row 0..63), cq = t&3 (16-k quarter)
    const int lr = t >> 2, cq = t & 3;
    const bool rv = (row0 + lr) < NN;
    const float* xrow = x + (size_t)(row0 + lr) * DF + cq * 16;

    float4 pf[4];
    #pragma unroll
    for (int j = 0; j < 4; ++j)
        pf[j] = rv ? *(const float4*)&xrow[4 * j] : make_float4(0.f, 0.f, 0.f, 0.f);

    float a0 = 0.f, a1 = 0.f, a2 = 0.f, a3 = 0.f;

    for (int kc = 0; kc < DF; kc += 64) {
        // write prefetched chunk
        #pragma unroll
        for (int j = 0; j < 4; ++j) {
            const int kb = cq * 16 + 4 * j;
            sX[lr * 65 + kb + 0] = pf[j].x;
            sX[lr * 65 + kb + 1] = pf[j].y;
            sX[lr * 65 + kb + 2] = pf[j].z;
            sX[lr * 65 + kb + 3] = pf[j].w;
        }
        __syncthreads();
        // prefetch next chunk
        if (kc + 64 < DF) {
            #pragma unroll
            for (int j = 0; j < 4; ++j)
                pf[j] = rv ? *(const float4*)&xrow[kc + 64 + 4 * j]
                           : make_float4(0.f, 0.f, 0.f, 0.f);
        }
        // compute: xv lane-indexed (bank (lane+k)%32, conflict-free); W wave-uniform
        #pragma unroll
        for (int k = 0; k < 64; ++k) {
            const float xv = sX[lane * 65 + k];
            const float4 wv = *(const float4*)&W1[(size_t)(kc + k) * NH + og * 4];
            a0 = fmaf(xv, wv.x, a0);
            a1 = fmaf(xv, wv.y, a1);
            a2 = fmaf(xv, wv.z, a2);
            a3 = fmaf(xv, wv.w, a3);
        }
        __syncthreads();
    }
    const int gr = row0 + lane;
    if (gr < NN) {
        const float s = dinv[gr];
        const u32 w0 = pack_bf2(a0 * s, a1 * s);
        const u32 w1 = pack_bf2(a2 * s, a3 * s);
        *(uint2*)&h1b[(size_t)gr * 8 + og * 2] = make_uint2(w0, w1);
    }
}

// ---------------------------------------------------------------- CSR gather agg, layer 1
// wave per node: lane = l (u32 col 0..7) + 8*g (edge group 0..7)
__global__ __launch_bounds__(1024) void k_agg1(
    const int* __restrict__ row_start, const int* __restrict__ degs,
    const int* __restrict__ esrc_s, const u32* __restrict__ h1b,
    const float* __restrict__ dinv, const float* __restrict__ b1,
    u32* __restrict__ A1) {
    const int node = blockIdx.x * 16 + (threadIdx.x >> 6);
    if (node >= NN) return;
    const int lane = threadIdx.x & 63;
    const int l = lane & 7;
    const int g = lane >> 3;
    const int beg = row_start[node];
    const int end = beg + degs[node];

    float a0 = 0.f, a1 = 0.f;
    int e = beg + g;
    for (; e + 8 < end; e += 16) {
        const int s0 = esrc_s[e];
        const int s1 = esrc_s[e + 8];
        const u32 u0 = h1b[(size_t)s0 * 8 + l];
        const u32 u1 = h1b[(size_t)s1 * 8 + l];
        a0 += bf_lo(u0); a1 += bf_hi(u0);
        a0 += bf_lo(u1); a1 += bf_hi(u1);
    }
    if (e < end) {
        const u32 u0 = h1b[(size_t)esrc_s[e] * 8 + l];
        a0 += bf_lo(u0); a1 += bf_hi(u0);
    }
    a0 += __shfl_xor(a0, 8);  a1 += __shfl_xor(a1, 8);
    a0 += __shfl_xor(a0, 16); a1 += __shfl_xor(a1, 16);
    a0 += __shfl_xor(a0, 32); a1 += __shfl_xor(a1, 32);

    if (g == 0) {
        const float dn = dinv[node];
        const u32 su = h1b[(size_t)node * 8 + l];
        const float p0 = (a0 + bf_lo(su)) * dn + b1[2 * l];
        const float p1 = (a1 + bf_hi(su)) * dn + b1[2 * l + 1];
        A1[(size_t)node * 8 + l] = pack_bf2(fmaxf(p0, 0.f) * dn, fmaxf(p1, 0.f) * dn);
    }
}

// ---------------------------------------------------------------- CSR gather agg, layer 2 + W2 + log_softmax
__global__ __launch_bounds__(1024) void k_agg2_final(
    const int* __restrict__ row_start, const int* __restrict__ degs,
    const int* __restrict__ esrc_s, const u32* __restrict__ A1,
    const float* __restrict__ dinv, const float* __restrict__ W2,
    const float* __restrict__ b2, float* __restrict__ out) {
    __shared__ float sW2[NH * NC];
    __shared__ float sb2[NC];
    const int t = threadIdx.x;
    if (t < NH * NC) sW2[t] = W2[t];
    if (t >= 1024 - NC) sb2[t - (1024 - NC)] = b2[t - (1024 - NC)];
    __syncthreads();

    const int node = blockIdx.x * 16 + (t >> 6);
    if (node >= NN) return;
    const int lane = t & 63;
    const int l = lane & 7;
    const int g = lane >> 3;
    const int beg = row_start[node];
    const int end = beg + degs[node];

    float a0 = 0.f, a1 = 0.f;
    int e = beg + g;
    for (; e + 8 < end; e += 16) {
        const int s0 = esrc_s[e];
        const int s1 = esrc_s[e + 8];
        const u32 u0 = A1[(size_t)s0 * 8 + l];
        const u32 u1 = A1[(size_t)s1 * 8 + l];
        a0 += bf_lo(u0); a1 += bf_hi(u0);
        a0 += bf_lo(u1); a1 += bf_hi(u1);
    }
    if (e < end) {
        const u32 u0 = A1[(size_t)esrc_s[e] * 8 + l];
        a0 += bf_lo(u0); a1 += bf_hi(u0);
    }
    a0 += __shfl_xor(a0, 8);  a1 += __shfl_xor(a1, 8);
    a0 += __shfl_xor(a0, 16); a1 += __shfl_xor(a1, 16);
    a0 += __shfl_xor(a0, 32); a1 += __shfl_xor(a1, 32);

    const float dn = dinv[node];
    const u32 su = A1[(size_t)node * 8 + l];
    const float ag0 = (a0 + bf_lo(su)) * dn;   // channel 2l
    const float ag1 = (a1 + bf_hi(su)) * dn;   // channel 2l+1

    float z = (lane < NC) ? sb2[lane] : -1e30f;
    #pragma unroll
    for (int k = 0; k < 8; ++k) {
        const float v0 = __shfl(ag0, k);
        const float v1 = __shfl(ag1, k);
        if (lane < NC) {
            z = fmaf(v0, sW2[(2 * k) * NC + lane], z);
            z = fmaf(v1, sW2[(2 * k + 1) * NC + lane], z);
        }
    }
    float m = z;
    #pragma unroll
    for (int off = 1; off < 64; off <<= 1) m = fmaxf(m, __shfl_xor(m, off));
    float sum = (lane < NC) ? __expf(z - m) : 0.f;
    #pragma unroll
    for (int off = 1; off < 64; off <<= 1) sum += __shfl_xor(sum, off);
    const float lse = m + __logf(sum);
    if (lane < NC) out[(size_t)node * NC + lane] = z - lse;
}

// ---------------------------------------------------------------- launch
extern "C" void kernel_launch(void* const* d_in, const int* in_sizes, int n_in,
                              void* d_out, int out_size, void* d_ws, size_t ws_size,
                              hipStream_t stream) {
    const float* x  = (const float*)d_in[0];
    const int*   ei = (const int*)d_in[1];   // [2, NE] flat int32
    const float* W1 = (const float*)d_in[2];
    const float* b1 = (const float*)d_in[3];
    const float* W2 = (const float*)d_in[4];
    const float* b2 = (const float*)d_in[5];
    float* out = (float*)d_out;

    // workspace (~37 MB)
    int* gcur      = (int*)d_ws;                           // NB
    u32* pairs     = (u32*)(gcur + NB);                    // NB*CAP
    int* esrc_s    = (int*)(pairs + (size_t)NB * CAP);     // NB*CAP
    int* row_start = esrc_s + (size_t)NB * CAP;            // NN
    int* degs      = row_start + NN;                       // NN
    float* dinv    = (float*)(degs + NN);                  // NN
    u32* h1b       = (u32*)(dinv + NN);                    // NN*8
    u32* A1        = h1b + (size_t)NN * 8;                 // NN*8

    const int* esrc = ei;
    const int* edst = ei + NE;

    k_init          <<<(NB + 255) / 256, 256, 0, stream>>>(gcur);
    k_scatter_bucket<<<SGRID, 1024, 0, stream>>>(esrc, edst, gcur, pairs);
    k_sort_bucket   <<<NB, 1024, 0, stream>>>(pairs, gcur, esrc_s, row_start, degs, dinv);
    k_gemm1         <<<(NN + 63) / 64, 256, 0, stream>>>(x, W1, dinv, h1b);
    k_agg1          <<<(NN + 15) / 16, 1024, 0, stream>>>(row_start, degs, esrc_s, h1b, dinv, b1, A1);
    k_agg2_final    <<<(NN + 15) / 16, 1024, 0, stream>>>(row_start, degs, esrc_s, A1, dinv, W2, b2, out);
}

// Round 7
// 213.198 us; speedup vs baseline: 25.8666x; 1.0617x over previous
//
#include <hip/hip_runtime.h>
#include <math.h>

typedef unsigned int u32;

constexpr int NN = 100000;   // nodes
constexpr int NE = 3200000;  // edges
constexpr int DF = 512;      // in features
constexpr int NH = 16;       // hidden
constexpr int NC = 40;       // classes

constexpr int NB  = 512;     // buckets
constexpr int BSZ = 196;     // nodes per bucket (512*196 >= NN)
constexpr int CAP = 7168;    // per-bucket edge capacity (mean 6250, +11 sigma)
constexpr int SCHUNK = 16384;
constexpr int SGRID  = (NE + SCHUNK - 1) / SCHUNK;

// ---------------------------------------------------------------- bf16 helpers
__device__ __forceinline__ u32 pack_bf2(float lo, float hi) {
    u32 a = __float_as_uint(lo), b = __float_as_uint(hi);
    a += 0x7FFFu + ((a >> 16) & 1u);   // RNE
    b += 0x7FFFu + ((b >> 16) & 1u);
    return (a >> 16) | (b & 0xFFFF0000u);
}
__device__ __forceinline__ float bf_lo(u32 u) { return __uint_as_float(u << 16); }
__device__ __forceinline__ float bf_hi(u32 u) { return __uint_as_float(u & 0xFFFF0000u); }

// ---------------------------------------------------------------- init bucket cursors
__global__ void k_init(int* __restrict__ gcur) {
    int i = blockIdx.x * blockDim.x + threadIdx.x;
    if (i < NB) gcur[i] = i * CAP;
}

// ---------------------------------------------------------------- bucket counting-scatter
// (dst,src) cached in registers across the two passes: edge list read once.
__global__ __launch_bounds__(1024) void k_scatter_bucket(
    const int* __restrict__ src, const int* __restrict__ dst,
    int* __restrict__ gcur, u32* __restrict__ pairs) {
    __shared__ int hist[NB];
    __shared__ int gpos[NB];
    __shared__ int lcur[NB];
    const int t = threadIdx.x;
    for (int i = t; i < NB; i += 1024) { hist[i] = 0; lcur[i] = 0; }
    __syncthreads();

    const int base = blockIdx.x * SCHUNK;
    int dr[SCHUNK / 1024], sr[SCHUNK / 1024];
    #pragma unroll
    for (int k = 0; k < SCHUNK / 1024; ++k) {
        const int i = base + k * 1024 + t;
        if (i < NE) {
            dr[k] = dst[i];
            sr[k] = src[i];
            atomicAdd(&hist[(unsigned)dr[k] / BSZ], 1);
        }
    }
    __syncthreads();
    for (int i = t; i < NB; i += 1024)
        if (hist[i]) gpos[i] = atomicAdd(&gcur[i], hist[i]);
    __syncthreads();
    #pragma unroll
    for (int k = 0; k < SCHUNK / 1024; ++k) {
        const int i = base + k * 1024 + t;
        if (i < NE) {
            const unsigned d = (unsigned)dr[k];
            const unsigned b = d / BSZ;
            const unsigned dl = d - b * BSZ;
            const int off = atomicAdd(&lcur[b], 1);
            pairs[gpos[b] + off] = (unsigned)sr[k] | (dl << 17);
        }
    }
}

// ---------------------------------------------------------------- per-bucket counting sort by dl
__global__ __launch_bounds__(1024) void k_sort_bucket(
    const u32* __restrict__ pairs, const int* __restrict__ gcur,
    int* __restrict__ esrc_s, int* __restrict__ row_start,
    int* __restrict__ degs, float* __restrict__ dinv) {
    __shared__ int hist[BSZ];
    __shared__ int scan[256];
    __shared__ int cur[BSZ];
    const int b = blockIdx.x, t = threadIdx.x;
    if (t < BSZ) hist[t] = 0;
    __syncthreads();

    const int base = b * CAP;
    const int end  = gcur[b];
    for (int p = base + t; p < end; p += 1024)
        atomicAdd(&hist[pairs[p] >> 17], 1);
    __syncthreads();

    const int h = (t < BSZ) ? hist[t] : 0;
    if (t < 256) scan[t] = (t < BSZ) ? h : 0;
    __syncthreads();
    #pragma unroll
    for (int off = 1; off < 256; off <<= 1) {
        int u = 0;
        if (t < 256 && t >= off) u = scan[t - off];
        __syncthreads();
        if (t < 256) scan[t] += u;
        __syncthreads();
    }
    if (t < BSZ) {
        const int st = scan[t] - h;   // exclusive
        cur[t] = st;
        const int n = b * BSZ + t;
        if (n < NN) {
            row_start[n] = base + st;
            degs[n] = h;
            dinv[n] = rsqrtf((float)(h + 1));
        }
    }
    __syncthreads();
    for (int p = base + t; p < end; p += 1024) {
        const u32 u = pairs[p];
        const int dl = u >> 17;
        const int pos = atomicAdd(&cur[dl], 1);
        esrc_s[base + pos] = (int)(u & 0x1FFFFu);
    }
}

// ---------------------------------------------------------------- layer-1 GEMM
// h1b[n] = bf16x16 row of (x[n] @ W1) * dinv[n]
// Pure-LDS inner loop: x tile stride-65 (conflict-free b32), W chunk staged
// per-kc in LDS read as broadcast b128. Register-prefetch double buffer on x/W.
__global__ __launch_bounds__(256) void k_gemm1(
    const float* __restrict__ x, const float* __restrict__ W1,
    const float* __restrict__ dinv, u32* __restrict__ h1b) {
    __shared__ float sX[64 * 65];   // 16.6 KB
    __shared__ float sW[64 * 16];   // 4 KB: W1 rows kc..kc+63
    const int t    = threadIdx.x;
    const int lane = t & 63;
    const int og   = t >> 6;   // wave id 0..3 -> output cols 4*og..4*og+3

    const int row0 = blockIdx.x * 64;
    const int lr = t >> 2, cq = t & 3;   // loader: row lr, 16-col quarter cq
    const bool rv = (row0 + lr) < NN;
    const float* xrow = x + (size_t)(row0 + lr) * DF + cq * 16;

    float4 pf[4];
    #pragma unroll
    for (int j = 0; j < 4; ++j)
        pf[j] = rv ? *(const float4*)&xrow[4 * j] : make_float4(0.f, 0.f, 0.f, 0.f);
    float4 wpf = *(const float4*)&W1[t * 4];   // chunk 0: floats [0,1024)

    float a0 = 0.f, a1 = 0.f, a2 = 0.f, a3 = 0.f;

    for (int kc = 0; kc < DF; kc += 64) {
        // write prefetched chunk to LDS
        #pragma unroll
        for (int j = 0; j < 4; ++j) {
            const int kb = cq * 16 + 4 * j;
            sX[lr * 65 + kb + 0] = pf[j].x;
            sX[lr * 65 + kb + 1] = pf[j].y;
            sX[lr * 65 + kb + 2] = pf[j].z;
            sX[lr * 65 + kb + 3] = pf[j].w;
        }
        *(float4*)&sW[t * 4] = wpf;
        __syncthreads();
        // prefetch next chunk
        if (kc + 64 < DF) {
            #pragma unroll
            for (int j = 0; j < 4; ++j)
                pf[j] = rv ? *(const float4*)&xrow[kc + 64 + 4 * j]
                           : make_float4(0.f, 0.f, 0.f, 0.f);
            wpf = *(const float4*)&W1[(kc + 64) * NH + t * 4];
        }
        // compute: x via conflict-free b32, W via broadcast b128
        #pragma unroll
        for (int k = 0; k < 64; ++k) {
            const float xv = sX[lane * 65 + k];
            const float4 wv = *(const float4*)&sW[k * NH + og * 4];
            a0 = fmaf(xv, wv.x, a0);
            a1 = fmaf(xv, wv.y, a1);
            a2 = fmaf(xv, wv.z, a2);
            a3 = fmaf(xv, wv.w, a3);
        }
        __syncthreads();
    }
    const int gr = row0 + lane;
    if (gr < NN) {
        const float s = dinv[gr];
        const u32 w0 = pack_bf2(a0 * s, a1 * s);
        const u32 w1 = pack_bf2(a2 * s, a3 * s);
        *(uint2*)&h1b[(size_t)gr * 8 + og * 2] = make_uint2(w0, w1);
    }
}

// ---------------------------------------------------------------- CSR gather agg, layer 1
// wave per node: lane = l (u32 col 0..7) + 8*g (edge group 0..7)
__global__ __launch_bounds__(1024) void k_agg1(
    const int* __restrict__ row_start, const int* __restrict__ degs,
    const int* __restrict__ esrc_s, const u32* __restrict__ h1b,
    const float* __restrict__ dinv, const float* __restrict__ b1,
    u32* __restrict__ A1) {
    const int node = blockIdx.x * 16 + (threadIdx.x >> 6);
    if (node >= NN) return;
    const int lane = threadIdx.x & 63;
    const int l = lane & 7;
    const int g = lane >> 3;
    const int beg = row_start[node];
    const int end = beg + degs[node];

    float a0 = 0.f, a1 = 0.f;
    int e = beg + g;
    for (; e + 8 < end; e += 16) {
        const int s0 = esrc_s[e];
        const int s1 = esrc_s[e + 8];
        const u32 u0 = h1b[(size_t)s0 * 8 + l];
        const u32 u1 = h1b[(size_t)s1 * 8 + l];
        a0 += bf_lo(u0); a1 += bf_hi(u0);
        a0 += bf_lo(u1); a1 += bf_hi(u1);
    }
    if (e < end) {
        const u32 u0 = h1b[(size_t)esrc_s[e] * 8 + l];
        a0 += bf_lo(u0); a1 += bf_hi(u0);
    }
    a0 += __shfl_xor(a0, 8);  a1 += __shfl_xor(a1, 8);
    a0 += __shfl_xor(a0, 16); a1 += __shfl_xor(a1, 16);
    a0 += __shfl_xor(a0, 32); a1 += __shfl_xor(a1, 32);

    if (g == 0) {
        const float dn = dinv[node];
        const u32 su = h1b[(size_t)node * 8 + l];
        const float p0 = (a0 + bf_lo(su)) * dn + b1[2 * l];
        const float p1 = (a1 + bf_hi(su)) * dn + b1[2 * l + 1];
        A1[(size_t)node * 8 + l] = pack_bf2(fmaxf(p0, 0.f) * dn, fmaxf(p1, 0.f) * dn);
    }
}

// ---------------------------------------------------------------- CSR gather agg, layer 2 + W2 + log_softmax
__global__ __launch_bounds__(1024) void k_agg2_final(
    const int* __restrict__ row_start, const int* __restrict__ degs,
    const int* __restrict__ esrc_s, const u32* __restrict__ A1,
    const float* __restrict__ dinv, const float* __restrict__ W2,
    const float* __restrict__ b2, float* __restrict__ out) {
    __shared__ float sW2[NH * NC];
    __shared__ float sb2[NC];
    const int t = threadIdx.x;
    if (t < NH * NC) sW2[t] = W2[t];
    if (t >= 1024 - NC) sb2[t - (1024 - NC)] = b2[t - (1024 - NC)];
    __syncthreads();

    const int node = blockIdx.x * 16 + (t >> 6);
    if (node >= NN) return;
    const int lane = t & 63;
    const int l = lane & 7;
    const int g = lane >> 3;
    const int beg = row_start[node];
    const int end = beg + degs[node];

    float a0 = 0.f, a1 = 0.f;
    int e = beg + g;
    for (; e + 8 < end; e += 16) {
        const int s0 = esrc_s[e];
        const int s1 = esrc_s[e + 8];
        const u32 u0 = A1[(size_t)s0 * 8 + l];
        const u32 u1 = A1[(size_t)s1 * 8 + l];
        a0 += bf_lo(u0); a1 += bf_hi(u0);
        a0 += bf_lo(u1); a1 += bf_hi(u1);
    }
    if (e < end) {
        const u32 u0 = A1[(size_t)esrc_s[e] * 8 + l];
        a0 += bf_lo(u0); a1 += bf_hi(u0);
    }
    a0 += __shfl_xor(a0, 8);  a1 += __shfl_xor(a1, 8);
    a0 += __shfl_xor(a0, 16); a1 += __shfl_xor(a1, 16);
    a0 += __shfl_xor(a0, 32); a1 += __shfl_xor(a1, 32);

    const float dn = dinv[node];
    const u32 su = A1[(size_t)node * 8 + l];
    const float ag0 = (a0 + bf_lo(su)) * dn;   // channel 2l
    const float ag1 = (a1 + bf_hi(su)) * dn;   // channel 2l+1

    float z = (lane < NC) ? sb2[lane] : -1e30f;
    #pragma unroll
    for (int k = 0; k < 8; ++k) {
        const float v0 = __shfl(ag0, k);
        const float v1 = __shfl(ag1, k);
        if (lane < NC) {
            z = fmaf(v0, sW2[(2 * k) * NC + lane], z);
            z = fmaf(v1, sW2[(2 * k + 1) * NC + lane], z);
        }
    }
    float m = z;
    #pragma unroll
    for (int off = 1; off < 64; off <<= 1) m = fmaxf(m, __shfl_xor(m, off));
    float sum = (lane < NC) ? __expf(z - m) : 0.f;
    #pragma unroll
    for (int off = 1; off < 64; off <<= 1) sum += __shfl_xor(sum, off);
    const float lse = m + __logf(sum);
    if (lane < NC) out[(size_t)node * NC + lane] = z - lse;
}

// ---------------------------------------------------------------- launch
extern "C" void kernel_launch(void* const* d_in, const int* in_sizes, int n_in,
                              void* d_out, int out_size, void* d_ws, size_t ws_size,
                              hipStream_t stream) {
    const float* x  = (const float*)d_in[0];
    const int*   ei = (const int*)d_in[1];   // [2, NE] flat int32
    const float* W1 = (const float*)d_in[2];
    const float* b1 = (const float*)d_in[3];
    const float* W2 = (const float*)d_in[4];
    const float* b2 = (const float*)d_in[5];
    float* out = (float*)d_out;

    // workspace (~37 MB)
    int* gcur      = (int*)d_ws;                           // NB
    u32* pairs     = (u32*)(gcur + NB);                    // NB*CAP
    int* esrc_s    = (int*)(pairs + (size_t)NB * CAP);     // NB*CAP
    int* row_start = esrc_s + (size_t)NB * CAP;            // NN
    int* degs      = row_start + NN;                       // NN
    float* dinv    = (float*)(degs + NN);                  // NN
    u32* h1b       = (u32*)(dinv + NN);                    // NN*8
    u32* A1        = h1b + (size_t)NN * 8;                 // NN*8

    const int* esrc = ei;
    const int* edst = ei + NE;

    k_init          <<<(NB + 255) / 256, 256, 0, stream>>>(gcur);
    k_scatter_bucket<<<SGRID, 1024, 0, stream>>>(esrc, edst, gcur, pairs);
    k_sort_bucket   <<<NB, 1024, 0, stream>>>(pairs, gcur, esrc_s, row_start, degs, dinv);
    k_gemm1         <<<(NN + 63) / 64, 256, 0, stream>>>(x, W1, dinv, h1b);
    k_agg1          <<<(NN + 15) / 16, 1024, 0, stream>>>(row_start, degs, esrc_s, h1b, dinv, b1, A1);
    k_agg2_final    <<<(NN + 15) / 16, 1024, 0, stream>>>(row_start, degs, esrc_s, A1, dinv, W2, b2, out);
}